// Round 16
// baseline (2199.301 us; speedup 1.0000x reference)
//
#include <hip/hip_runtime.h>
#include <hip/hip_bf16.h>
#include <math.h>

#define DEVI __device__ __forceinline__
typedef __attribute__((ext_vector_type(8))) short bf16x8;
typedef __attribute__((ext_vector_type(4))) float f32x4;

#define MFMA(a, b, c) __builtin_amdgcn_mfma_f32_16x16x32_bf16((a), (b), (c), 0, 0, 0)

DEVI short f2bf(float f) {
    unsigned u = __builtin_bit_cast(unsigned, f);
    return (short)((u + 0x7FFFu + ((u >> 16) & 1u)) >> 16);
}
DEVI float bf2f(short s) {
    unsigned u = ((unsigned)(unsigned short)s) << 16;
    return __builtin_bit_cast(float, u);
}
// 128B-row tiles: 3-bit row XOR (8 slots)
DEVI int swz8(int row, int cb, int ld) { return row * ld + (cb ^ ((row & 7) << 4)); }
// >=256B-row tiles: 4-bit row XOR (16 slots)
DEVI int swz16(int row, int cb, int ld) { return row * ld + (cb ^ ((row & 15) << 4)); }
DEVI bf16x8 gload_bf8(const float* p) {
    const f32x4* q = (const f32x4*)p;
    f32x4 a = q[0], b = q[1];
    bf16x8 r;
    r[0] = f2bf(a[0]); r[1] = f2bf(a[1]); r[2] = f2bf(a[2]); r[3] = f2bf(a[3]);
    r[4] = f2bf(b[0]); r[5] = f2bf(b[1]); r[6] = f2bf(b[2]); r[7] = f2bf(b[3]);
    return r;
}

// Weight prep: fp32 row-major [rows][Kd] -> bf16 MFMA fragment order.
__global__ void prep_frag(const float* __restrict__ s, short* __restrict__ d,
                          int kd32, int n) {
    int i = blockIdx.x * 256 + threadIdx.x;
    if (i >= n) return;
    int lane = i & 63;
    int gt = i >> 6;
    int g = gt % kd32, tile = gt / kd32;
    int j = tile * 16 + (lane & 15);
    int k0 = g * 32 + (lane >> 4) * 8;
    int Kd = kd32 * 32;
    bf16x8 o = gload_bf8(s + (size_t)j * Kd + k0);
    *(bf16x8*)(d + (size_t)i * 8) = o;
}

// ============================================================================
// KA (round-15 base: XCD swizzle, swz16) + LDS-read pairing:
//  - QKV: waves 0-3 compute q-tile AND v-tile in ONE kk loop (4 SW reads feed
//    8 MFMA instead of 2x4 reads / 2x4 MFMA). Waves 4-7: k only (unchanged).
//  - out-proj: both ct tiles in one kk loop (4 OB reads feed 8 MFMA).
// Numerics bit-identical to round 15.
// ============================================================================
__global__ __launch_bounds__(512, 2) void swin_attn(
    const float* __restrict__ x,
    const float* __restrict__ n1w, const float* __restrict__ n1b,
    const short* __restrict__ WqB, const float* __restrict__ Bq,
    const short* __restrict__ WoB, const float* __restrict__ Bo,
    short* __restrict__ Rws)
{
    extern __shared__ __align__(16) char smem[];
    constexpr int OB = 0, CQ = 25088, CK = 31360, CV = 37632, SW = 50176, ST = 75264;

    // bijective XCD swizzle: 8192 = 8 * 1024
    const int bid = ((blockIdx.x & 7) << 10) + (blockIdx.x >> 3);
    const int b = bid >> 10, wh = (bid >> 5) & 31, w7 = bid & 31;
    const int tid = threadIdx.x, wv = tid >> 6, lane = tid & 63;
    const int lg = lane >> 4, l15 = lane & 15;
    const int c0 = wv * 32 + l15;
    const f32x4 z = {0.f, 0.f, 0.f, 0.f};

    {
        float* sX = (float*)smem;
        const float* xb = x + (size_t)b * (256 * 224 * 224);
        for (int i = tid; i < 256 * 49; i += 512) {
            int c = i / 49, l = i - c * 49;
            int hh = wh * 7 + l / 7, ww = w7 * 7 + (l % 7);
            sX[i] = xb[((size_t)c * 224 + hh) * 224 + ww];
        }
    }
    __syncthreads();
    {
        const int l = tid >> 3, s = tid & 7;
        if (l < 49) {
            const float* sX = (const float*)smem;
            float sum = 0.f, sq = 0.f;
            for (int ii = 0; ii < 32; ++ii) {
                int c = s * 32 + ((ii + tid) & 31);
                float v = sX[c * 49 + l];
                sum += v; sq += v * v;
            }
#pragma unroll
            for (int m = 1; m < 8; m <<= 1) { sum += __shfl_xor(sum, m); sq += __shfl_xor(sq, m); }
            if (s == 0) {
                float mean = sum * (1.f / 256.f);
                ((float*)(smem + ST))[l * 2] = mean;
                ((float*)(smem + ST))[l * 2 + 1] = rsqrtf(sq * (1.f / 256.f) - mean * mean + 1e-5f);
            }
        }
    }
    __syncthreads();
    {
        const float* sX = (const float*)smem;
        const float* st = (const float*)(smem + ST);
        float w0 = n1w[c0], b0 = n1b[c0], w1 = n1w[c0 + 16], b1 = n1b[c0 + 16];
#pragma unroll
        for (int ct = 0; ct < 2; ++ct)
#pragma unroll
        for (int mt = 0; mt < 4; ++mt)
#pragma unroll
        for (int r = 0; r < 4; ++r) {
            int row = mt * 16 + lg * 4 + r, col = c0 + ct * 16;
            if (row < 49) {
                float v = (sX[col * 49 + row] - st[row * 2]) * st[row * 2 + 1] * (ct ? w1 : w0) + (ct ? b1 : b0);
                *(short*)(smem + SW + swz16(row, col * 2, 512)) = f2bf(v);
            }
        }
    }
    __syncthreads();

    const int grp = wv >> 2, mts = wv & 3;
    int arow = mts * 16 + l15; if (arow > 48) arow = 48;
#pragma unroll 1
    for (int hp = 0; hp < 4; ++hp) {
        // ---- QKV paired: waves 0-3: q + v tiles (shared SW reads); 4-7: k ----
        {
            const int part = wv >> 2, tt = wv & 3;
            const int lc = tt * 16 + l15;
            const int jw = part * 256 + hp * 64 + lc;      // q (part0) or k (part1)
            const int wtile = part * 16 + hp * 4 + tt;
            const int jv = 512 + hp * 64 + lc;             // v (waves 0-3 only)
            const int wtv = 32 + hp * 4 + tt;
            f32x4 a0 = z, a1 = z, a2 = z, a3 = z;          // q or k
            f32x4 b0 = z, b1 = z, b2 = z, b3 = z;          // v
#pragma unroll
            for (int kk = 0; kk < 8; ++kk) {
                const int cb = kk * 64 + lg * 16;
                bf16x8 f0 = *(const bf16x8*)(smem + SW + swz16(l15, cb, 512));
                bf16x8 f1 = *(const bf16x8*)(smem + SW + swz16(16 + l15, cb, 512));
                bf16x8 f2 = *(const bf16x8*)(smem + SW + swz16(32 + l15, cb, 512));
                bf16x8 f3 = *(const bf16x8*)(smem + SW + swz16(48, cb, 512));
                bf16x8 bw = *(const bf16x8*)(WqB + (((size_t)(wtile * 8 + kk) * 64 + lane) << 3));
                a0 = MFMA(f0, bw, a0); a1 = MFMA(f1, bw, a1);
                a2 = MFMA(f2, bw, a2); a3 = MFMA(f3, bw, a3);
                if (part == 0) {
                    bf16x8 bv = *(const bf16x8*)(WqB + (((size_t)(wtv * 8 + kk) * 64 + lane) << 3));
                    b0 = MFMA(f0, bv, b0); b1 = MFMA(f1, bv, b1);
                    b2 = MFMA(f2, bv, b2); b3 = MFMA(f3, bv, b3);
                }
            }
            {   // store q (part0) or k (part1)
                const float bias = Bq[jw];
                char* base = smem + (part ? CK : CQ);
#pragma unroll
                for (int mt = 0; mt < 4; ++mt) {
                    f32x4 av = (mt == 0) ? a0 : (mt == 1) ? a1 : (mt == 2) ? a2 : a3;
#pragma unroll
                    for (int r = 0; r < 4; ++r) {
                        int row = mt * 16 + lg * 4 + r;
                        if (row < 49) *(short*)(base + swz8(row, lc * 2, 128)) = f2bf(av[r] + bias);
                    }
                }
            }
            if (part == 0) {   // store v transposed
                const float bias = Bq[jv];
#pragma unroll
                for (int mt = 0; mt < 4; ++mt) {
                    f32x4 av = (mt == 0) ? b0 : (mt == 1) ? b1 : (mt == 2) ? b2 : b3;
#pragma unroll
                    for (int r = 0; r < 4; ++r) {
                        int row = mt * 16 + lg * 4 + r;
                        *(short*)(smem + CV + swz8(lc, row * 2, 128)) = f2bf(av[r] + bias);
                    }
                }
            }
        }
        __syncthreads();
        const int hb = grp * 64 + lg * 16;
        f32x4 s0 = z, s1 = z, s2 = z, s3 = z;
        {
            bf16x8 qa = *(const bf16x8*)(smem + CQ + swz8(arow, hb, 128));
            bf16x8 k0 = *(const bf16x8*)(smem + CK + swz8(l15, hb, 128));
            bf16x8 k1 = *(const bf16x8*)(smem + CK + swz8(16 + l15, hb, 128));
            bf16x8 k2 = *(const bf16x8*)(smem + CK + swz8(32 + l15, hb, 128));
            bf16x8 k3 = *(const bf16x8*)(smem + CK + swz8(48, hb, 128));
            s0 = MFMA(qa, k0, s0); s1 = MFMA(qa, k1, s1);
            s2 = MFMA(qa, k2, s2); s3 = MFMA(qa, k3, s3);
        }
        const float scale = 0.17677669529663687f;
        float pr[4][4];
#pragma unroll
        for (int rj = 0; rj < 4; ++rj) {
            float v0 = s0[rj] * scale, v1 = s1[rj] * scale;
            float v2 = s2[rj] * scale, v3 = s3[rj] * scale;
            const int c3 = 48 + l15;
            float mx = fmaxf(fmaxf(v0, v1), v2);
            if (c3 < 49) mx = fmaxf(mx, v3);
#pragma unroll
            for (int mm = 1; mm < 16; mm <<= 1) mx = fmaxf(mx, __shfl_xor(mx, mm));
            float e0 = __expf(v0 - mx), e1 = __expf(v1 - mx), e2 = __expf(v2 - mx);
            float e3 = (c3 < 49) ? __expf(v3 - mx) : 0.f;
            float sm = e0 + e1 + e2 + e3;
#pragma unroll
            for (int mm = 1; mm < 16; mm <<= 1) sm += __shfl_xor(sm, mm);
            float inv = 1.f / sm;
            pr[rj][0] = e0 * inv; pr[rj][1] = e1 * inv;
            pr[rj][2] = e2 * inv; pr[rj][3] = e3 * inv;
        }
        __syncthreads();
        char* satt = smem + CQ + grp * 6272;
#pragma unroll
        for (int rj = 0; rj < 4; ++rj) {
            int row = mts * 16 + lg * 4 + rj;
            if (row < 49) {
                *(short*)(satt + swz8(row, l15 * 2, 128)) = f2bf(pr[rj][0]);
                *(short*)(satt + swz8(row, (16 + l15) * 2, 128)) = f2bf(pr[rj][1]);
                *(short*)(satt + swz8(row, (32 + l15) * 2, 128)) = f2bf(pr[rj][2]);
                *(short*)(satt + swz8(row, (48 + l15) * 2, 128)) = f2bf(pr[rj][3]);
            }
        }
        __syncthreads();
        f32x4 o0 = z, o1 = z;
#pragma unroll
        for (int kk = 0; kk < 2; ++kk) {
            const int kb = kk * 64 + lg * 16;
            bf16x8 pa  = *(const bf16x8*)(satt + swz8(arow, kb, 128));
            bf16x8 vb0 = *(const bf16x8*)(smem + CV + swz8(grp * 32 + l15, kb, 128));
            bf16x8 vb1 = *(const bf16x8*)(smem + CV + swz8(grp * 32 + 16 + l15, kb, 128));
            o0 = MFMA(pa, vb0, o0); o1 = MFMA(pa, vb1, o1);
        }
#pragma unroll
        for (int nt = 0; nt < 2; ++nt) {
            f32x4 ov = nt ? o1 : o0;
#pragma unroll
            for (int r = 0; r < 4; ++r) {
                int row = mts * 16 + lg * 4 + r;
                if (row < 49) {
                    int col = hp * 64 + grp * 32 + nt * 16 + l15;
                    *(short*)(smem + OB + swz16(row, col * 2, 512)) = f2bf(ov[r]);
                }
            }
        }
        __syncthreads();
    }

    // ---- out-proj paired: both ct tiles share the 4 OB reads per kk ----
    {
        const int j0 = c0, j1 = c0 + 16;
        f32x4 a0 = z, a1 = z, a2 = z, a3 = z;     // ct = 0
        f32x4 c4 = z, c5 = z, c6 = z, c7 = z;     // ct = 1
#pragma unroll
        for (int kk = 0; kk < 8; ++kk) {
            const int cb = kk * 64 + lg * 16;
            bf16x8 f0 = *(const bf16x8*)(smem + OB + swz16(l15, cb, 512));
            bf16x8 f1 = *(const bf16x8*)(smem + OB + swz16(16 + l15, cb, 512));
            bf16x8 f2 = *(const bf16x8*)(smem + OB + swz16(32 + l15, cb, 512));
            bf16x8 f3 = *(const bf16x8*)(smem + OB + swz16(48, cb, 512));
            bf16x8 bw0 = *(const bf16x8*)(WoB + (((size_t)((wv * 2) * 8 + kk) * 64 + lane) << 3));
            bf16x8 bw1 = *(const bf16x8*)(WoB + (((size_t)((wv * 2 + 1) * 8 + kk) * 64 + lane) << 3));
            a0 = MFMA(f0, bw0, a0); a1 = MFMA(f1, bw0, a1);
            a2 = MFMA(f2, bw0, a2); a3 = MFMA(f3, bw0, a3);
            c4 = MFMA(f0, bw1, c4); c5 = MFMA(f1, bw1, c5);
            c6 = MFMA(f2, bw1, c6); c7 = MFMA(f3, bw1, c7);
        }
        const float bias0 = Bo[j0], bias1 = Bo[j1];
#pragma unroll
        for (int mt = 0; mt < 4; ++mt) {
            f32x4 av = (mt == 0) ? a0 : (mt == 1) ? a1 : (mt == 2) ? a2 : a3;
            f32x4 cv = (mt == 0) ? c4 : (mt == 1) ? c5 : (mt == 2) ? c6 : c7;
#pragma unroll
            for (int r = 0; r < 4; ++r) {
                int row = mt * 16 + lg * 4 + r;
                if (row < 49) {
                    short* p0 = (short*)(smem + SW + swz16(row, j0 * 2, 512));
                    *p0 = f2bf(bf2f(*p0) + av[r] + bias0);
                    short* p1 = (short*)(smem + SW + swz16(row, j1 * 2, 512));
                    *p1 = f2bf(bf2f(*p1) + cv[r] + bias1);
                }
            }
        }
    }
    __syncthreads();
    {
        for (int i = tid; i < 49 * 32; i += 512) {
            int row = i >> 5, c8 = (i & 31) * 8;
            bf16x8 v = *(const bf16x8*)(smem + SW + swz16(row, c8 * 2, 512));
            *(bf16x8*)(Rws + ((size_t)bid * 49 + row) * 256 + c8) = v;
        }
    }
}

// ============================================================================
// KB v7 (round-15 exact): 16 waves, chunk=128, swz16 Z/H, H double-buffer,
// XCD swizzle (3136 = 8 * 392). Measured 1176 us.
// ============================================================================
__global__ __launch_bounds__(1024, 1) void mlp_kernel(
    const short* __restrict__ Rws,
    const float* __restrict__ n2w, const float* __restrict__ n2b,
    const short* __restrict__ W1B, const float* __restrict__ B1,
    const short* __restrict__ W2B, const float* __restrict__ B2,
    float* __restrict__ out)
{
    extern __shared__ __align__(16) char smem[];
    constexpr int HB0 = 65536, HB1 = 98304;
    const int tile = (blockIdx.x & 7) * 392 + (blockIdx.x >> 3);
    const int tid = threadIdx.x, wv = tid >> 6, lane = tid & 63;
    const int lg = lane >> 4, l15 = lane & 15;
    const int wm = wv >> 3, wn = wv & 7;
    const int r0 = wm * 64;
    const f32x4 z = {0.f, 0.f, 0.f, 0.f};

#pragma unroll
    for (int it = 0; it < 4; ++it) {
        int e = it * 1024 + tid;
        int row = e >> 5, c8 = (e & 31) * 8;
        bf16x8 v = *(const bf16x8*)(Rws + ((size_t)tile * 128 + row) * 256 + c8);
        *(bf16x8*)(smem + swz16(row, c8 * 2, 512)) = v;
    }
    __syncthreads();
    {
        const int row = tid >> 3, sub = tid & 7;
        bf16x8 vv[4];
        float sum = 0.f, sq = 0.f;
#pragma unroll
        for (int ii = 0; ii < 4; ++ii) {
            vv[ii] = *(const bf16x8*)(smem + swz16(row, (sub * 32 + ii * 8) * 2, 512));
#pragma unroll
            for (int j = 0; j < 8; ++j) { float f = bf2f(vv[ii][j]); sum += f; sq += f * f; }
        }
#pragma unroll
        for (int m = 1; m < 8; m <<= 1) { sum += __shfl_xor(sum, m); sq += __shfl_xor(sq, m); }
        const float mean = sum * (1.f / 256.f);
        const float rstd = rsqrtf(sq * (1.f / 256.f) - mean * mean + 1e-5f);
#pragma unroll
        for (int ii = 0; ii < 4; ++ii) {
            f32x4 w0 = *(const f32x4*)(n2w + sub * 32 + ii * 8);
            f32x4 w1 = *(const f32x4*)(n2w + sub * 32 + ii * 8 + 4);
            f32x4 b0 = *(const f32x4*)(n2b + sub * 32 + ii * 8);
            f32x4 b1 = *(const f32x4*)(n2b + sub * 32 + ii * 8 + 4);
            bf16x8 o;
#pragma unroll
            for (int j = 0; j < 8; ++j) {
                float wj = (j < 4) ? w0[j] : w1[j - 4];
                float bj = (j < 4) ? b0[j] : b1[j - 4];
                o[j] = f2bf((bf2f(vv[ii][j]) - mean) * rstd * wj + bj);
            }
            *(bf16x8*)(smem + swz16(row, (sub * 32 + ii * 8) * 2, 512)) = o;
        }
    }
    __syncthreads();

    f32x4 macc[8];
#pragma unroll
    for (int i = 0; i < 8; ++i) macc[i] = z;

#pragma unroll 1
    for (int c = 0; c < 8; ++c) {
        char* HB = smem + ((c & 1) ? HB1 : HB0);
        f32x4 g1[4];
#pragma unroll
        for (int i = 0; i < 4; ++i) g1[i] = z;
#pragma unroll
        for (int kk = 0; kk < 8; ++kk) {
            const int cb = kk * 64 + lg * 16;
            bf16x8 a0 = *(const bf16x8*)(smem + swz16(r0 + l15,      cb, 512));
            bf16x8 a1 = *(const bf16x8*)(smem + swz16(r0 + 16 + l15, cb, 512));
            bf16x8 a2 = *(const bf16x8*)(smem + swz16(r0 + 32 + l15, cb, 512));
            bf16x8 a3 = *(const bf16x8*)(smem + swz16(r0 + 48 + l15, cb, 512));
            const int t = c * 8 + wn;
            bf16x8 wf = *(const bf16x8*)(W1B + (((size_t)(t * 8 + kk) * 64 + lane) << 3));
            g1[0] = MFMA(a0, wf, g1[0]);
            g1[1] = MFMA(a1, wf, g1[1]);
            g1[2] = MFMA(a2, wf, g1[2]);
            g1[3] = MFMA(a3, wf, g1[3]);
        }
        {
            const int hc = wn * 16 + l15;
            const float bias = B1[c * 128 + hc];
#pragma unroll
            for (int mt = 0; mt < 4; ++mt) {
#pragma unroll
                for (int r = 0; r < 4; ++r) {
                    int row = r0 + mt * 16 + lg * 4 + r;
                    float v = g1[mt][r] + bias;
                    float g = v / (1.f + __expf(-v * (1.595769122f + 0.071354816f * v * v)));
                    *(short*)(HB + swz16(row, hc * 2, 256)) = f2bf(g);
                }
            }
        }
        __syncthreads();
#pragma unroll
        for (int ks = 0; ks < 4; ++ks) {
            const int cb = ks * 64 + lg * 16;
            bf16x8 h0 = *(const bf16x8*)(HB + swz16(r0 + l15,      cb, 256));
            bf16x8 h1 = *(const bf16x8*)(HB + swz16(r0 + 16 + l15, cb, 256));
            bf16x8 h2 = *(const bf16x8*)(HB + swz16(r0 + 32 + l15, cb, 256));
            bf16x8 h3 = *(const bf16x8*)(HB + swz16(r0 + 48 + l15, cb, 256));
#pragma unroll
            for (int ct = 0; ct < 2; ++ct) {
                const int t2 = wn * 2 + ct;
                const int g = c * 4 + ks;
                bf16x8 wf = *(const bf16x8*)(W2B + (((size_t)(t2 * 32 + g) * 64 + lane) << 3));
                macc[ct * 4 + 0] = MFMA(h0, wf, macc[ct * 4 + 0]);
                macc[ct * 4 + 1] = MFMA(h1, wf, macc[ct * 4 + 1]);
                macc[ct * 4 + 2] = MFMA(h2, wf, macc[ct * 4 + 2]);
                macc[ct * 4 + 3] = MFMA(h3, wf, macc[ct * 4 + 3]);
            }
        }
    }
    __syncthreads();
    float* stg = (float*)smem;
#pragma unroll 1
    for (int half = 0; half < 2; ++half) {
        if (wm == half) {
#pragma unroll
            for (int ct = 0; ct < 2; ++ct) {
                const int col = wn * 32 + ct * 16 + l15;
                const float b2v = B2[col];
#pragma unroll
                for (int mt = 0; mt < 4; ++mt) {
#pragma unroll
                    for (int r = 0; r < 4; ++r) {
                        int rl = mt * 16 + lg * 4 + r;
                        size_t t = (size_t)tile * 128 + half * 64 + rl;
                        float rv = bf2f(Rws[t * 256 + col]);
                        stg[rl * 260 + col] = rv + macc[ct * 4 + mt][r] + b2v;
                    }
                }
            }
        }
        __syncthreads();
        for (int i = tid; i < 64 * 256; i += 1024) {
            int cc = i >> 6, rl = i & 63;
            int t = tile * 128 + half * 64 + rl;
            int win = t / 49, l = t - win * 49;
            int b = win >> 10, wh = (win >> 5) & 31, w7 = win & 31;
            out[((size_t)(b * 256 + cc) * 224 + wh * 7 + l / 7) * 224 + w7 * 7 + (l % 7)] =
                stg[rl * 260 + cc];
        }
        __syncthreads();
    }
}

extern "C" void kernel_launch(void* const* d_in, const int* in_sizes, int n_in,
                              void* d_out, int out_size, void* d_ws, size_t ws_size,
                              hipStream_t stream) {
    const float* x   = (const float*)d_in[0];
    const float* n1w = (const float*)d_in[1];
    const float* n1b = (const float*)d_in[2];
    const float* Wq  = (const float*)d_in[3];
    const float* Bq  = (const float*)d_in[4];
    const float* Wo  = (const float*)d_in[5];
    const float* Bo  = (const float*)d_in[6];
    const float* n2w = (const float*)d_in[7];
    const float* n2b = (const float*)d_in[8];
    const float* W1  = (const float*)d_in[9];
    const float* B1  = (const float*)d_in[10];
    const float* W2  = (const float*)d_in[11];
    const float* B2  = (const float*)d_in[12];
    float* out = (float*)d_out;
    (void)in_sizes; (void)n_in; (void)out_size; (void)ws_size;

    short* wsp = (short*)d_ws;
    short* WqF = wsp;                // 196608 shorts (fragment order)
    short* WoF = wsp + 196608;       // 65536
    short* W1F = wsp + 262144;       // 262144
    short* W2F = wsp + 524288;       // 262144  -> weights end at byte 1572864
    short* Rws = wsp + 786432;       // 401408*256 shorts = 205520896 B

    prep_frag<<<96, 256, 0, stream>>>(Wq, WqF, 8, 24576);   // 768x256
    prep_frag<<<32, 256, 0, stream>>>(Wo, WoF, 8, 8192);    // 256x256
    prep_frag<<<128, 256, 0, stream>>>(W1, W1F, 8, 32768);  // 1024x256
    prep_frag<<<128, 256, 0, stream>>>(W2, W2F, 32, 32768); // 256x1024

    swin_attn<<<8192, 512, 76288, stream>>>(x, n1w, n1b, WqF, Bq, WoF, Bo, Rws);
    mlp_kernel<<<3136, 1024, 131072, stream>>>(Rws, n2w, n2b, W1F, B1, W2F, B2, out);
}

// Round 17
// 2061.972 us; speedup vs baseline: 1.0666x; 1.0666x over previous
//
#include <hip/hip_runtime.h>
#include <hip/hip_bf16.h>
#include <math.h>

#define DEVI __device__ __forceinline__
typedef __attribute__((ext_vector_type(8))) short bf16x8;
typedef __attribute__((ext_vector_type(4))) float f32x4;

#define MFMA(a, b, c) __builtin_amdgcn_mfma_f32_16x16x32_bf16((a), (b), (c), 0, 0, 0)

DEVI short f2bf(float f) {
    unsigned u = __builtin_bit_cast(unsigned, f);
    return (short)((u + 0x7FFFu + ((u >> 16) & 1u)) >> 16);
}
DEVI float bf2f(short s) {
    unsigned u = ((unsigned)(unsigned short)s) << 16;
    return __builtin_bit_cast(float, u);
}
// 128B-row tiles: 3-bit row XOR (8 slots)
DEVI int swz8(int row, int cb, int ld) { return row * ld + (cb ^ ((row & 7) << 4)); }
// >=256B-row tiles: 4-bit row XOR (16 slots)
DEVI int swz16(int row, int cb, int ld) { return row * ld + (cb ^ ((row & 15) << 4)); }
DEVI bf16x8 gload_bf8(const float* p) {
    const f32x4* q = (const f32x4*)p;
    f32x4 a = q[0], b = q[1];
    bf16x8 r;
    r[0] = f2bf(a[0]); r[1] = f2bf(a[1]); r[2] = f2bf(a[2]); r[3] = f2bf(a[3]);
    r[4] = f2bf(b[0]); r[5] = f2bf(b[1]); r[6] = f2bf(b[2]); r[7] = f2bf(b[3]);
    return r;
}

// Weight prep: fp32 row-major [rows][Kd] -> bf16 MFMA fragment order.
__global__ void prep_frag(const float* __restrict__ s, short* __restrict__ d,
                          int kd32, int n) {
    int i = blockIdx.x * 256 + threadIdx.x;
    if (i >= n) return;
    int lane = i & 63;
    int gt = i >> 6;
    int g = gt % kd32, tile = gt / kd32;
    int j = tile * 16 + (lane & 15);
    int k0 = g * 32 + (lane >> 4) * 8;
    int Kd = kd32 * 32;
    bf16x8 o = gload_bf8(s + (size_t)j * Kd + k0);
    *(bf16x8*)(d + (size_t)i * 8) = o;
}

// ============================================================================
// KA: round-15 structure exactly (unpaired QKV — balanced phases beat fewer
// LDS reads: r16's q+v fusion put 2x work on waves 0-3 and regressed) with
// the ONLY r16 addition kept being the BALANCED out-proj pairing (all 8 waves
// identical; 4 OB reads feed 8 MFMA). XCD swizzle + swz16 as in round 15.
// ============================================================================
__global__ __launch_bounds__(512, 2) void swin_attn(
    const float* __restrict__ x,
    const float* __restrict__ n1w, const float* __restrict__ n1b,
    const short* __restrict__ WqB, const float* __restrict__ Bq,
    const short* __restrict__ WoB, const float* __restrict__ Bo,
    short* __restrict__ Rws)
{
    extern __shared__ __align__(16) char smem[];
    constexpr int OB = 0, CQ = 25088, CK = 31360, CV = 37632, SW = 50176, ST = 75264;

    // bijective XCD swizzle: 8192 = 8 * 1024
    const int bid = ((blockIdx.x & 7) << 10) + (blockIdx.x >> 3);
    const int b = bid >> 10, wh = (bid >> 5) & 31, w7 = bid & 31;
    const int tid = threadIdx.x, wv = tid >> 6, lane = tid & 63;
    const int lg = lane >> 4, l15 = lane & 15;
    const int c0 = wv * 32 + l15;
    const f32x4 z = {0.f, 0.f, 0.f, 0.f};

    {
        float* sX = (float*)smem;
        const float* xb = x + (size_t)b * (256 * 224 * 224);
        for (int i = tid; i < 256 * 49; i += 512) {
            int c = i / 49, l = i - c * 49;
            int hh = wh * 7 + l / 7, ww = w7 * 7 + (l % 7);
            sX[i] = xb[((size_t)c * 224 + hh) * 224 + ww];
        }
    }
    __syncthreads();
    {
        const int l = tid >> 3, s = tid & 7;
        if (l < 49) {
            const float* sX = (const float*)smem;
            float sum = 0.f, sq = 0.f;
            for (int ii = 0; ii < 32; ++ii) {
                int c = s * 32 + ((ii + tid) & 31);
                float v = sX[c * 49 + l];
                sum += v; sq += v * v;
            }
#pragma unroll
            for (int m = 1; m < 8; m <<= 1) { sum += __shfl_xor(sum, m); sq += __shfl_xor(sq, m); }
            if (s == 0) {
                float mean = sum * (1.f / 256.f);
                ((float*)(smem + ST))[l * 2] = mean;
                ((float*)(smem + ST))[l * 2 + 1] = rsqrtf(sq * (1.f / 256.f) - mean * mean + 1e-5f);
            }
        }
    }
    __syncthreads();
    {
        const float* sX = (const float*)smem;
        const float* st = (const float*)(smem + ST);
        float w0 = n1w[c0], b0 = n1b[c0], w1 = n1w[c0 + 16], b1 = n1b[c0 + 16];
#pragma unroll
        for (int ct = 0; ct < 2; ++ct)
#pragma unroll
        for (int mt = 0; mt < 4; ++mt)
#pragma unroll
        for (int r = 0; r < 4; ++r) {
            int row = mt * 16 + lg * 4 + r, col = c0 + ct * 16;
            if (row < 49) {
                float v = (sX[col * 49 + row] - st[row * 2]) * st[row * 2 + 1] * (ct ? w1 : w0) + (ct ? b1 : b0);
                *(short*)(smem + SW + swz16(row, col * 2, 512)) = f2bf(v);
            }
        }
    }
    __syncthreads();

    const int grp = wv >> 2, mts = wv & 3;
    int arow = mts * 16 + l15; if (arow > 48) arow = 48;
#pragma unroll 1
    for (int hp = 0; hp < 4; ++hp) {
#pragma unroll 1
        for (int sub = 0; sub < 2; ++sub) {
            if (sub == 0 || wv < 4) {
                const int t = sub ? (8 + wv) : wv;
                const int part = t >> 2, tt = t & 3;
                const int lc = tt * 16 + l15;
                const int jw = part * 256 + hp * 64 + lc;
                const int wtile = part * 16 + hp * 4 + tt;
                f32x4 a0 = z, a1 = z, a2 = z, a3 = z;
#pragma unroll
                for (int kk = 0; kk < 8; ++kk) {
                    bf16x8 bw = *(const bf16x8*)(WqB + (((size_t)(wtile * 8 + kk) * 64 + lane) << 3));
                    const int cb = kk * 64 + lg * 16;
                    bf16x8 f0 = *(const bf16x8*)(smem + SW + swz16(l15, cb, 512));
                    bf16x8 f1 = *(const bf16x8*)(smem + SW + swz16(16 + l15, cb, 512));
                    bf16x8 f2 = *(const bf16x8*)(smem + SW + swz16(32 + l15, cb, 512));
                    bf16x8 f3 = *(const bf16x8*)(smem + SW + swz16(48, cb, 512));
                    a0 = MFMA(f0, bw, a0); a1 = MFMA(f1, bw, a1);
                    a2 = MFMA(f2, bw, a2); a3 = MFMA(f3, bw, a3);
                }
                const float bias = Bq[jw];
                if (part < 2) {
                    char* base = smem + (part ? CK : CQ);
#pragma unroll
                    for (int mt = 0; mt < 4; ++mt) {
                        f32x4 av = (mt == 0) ? a0 : (mt == 1) ? a1 : (mt == 2) ? a2 : a3;
#pragma unroll
                        for (int r = 0; r < 4; ++r) {
                            int row = mt * 16 + lg * 4 + r;
                            if (row < 49) *(short*)(base + swz8(row, lc * 2, 128)) = f2bf(av[r] + bias);
                        }
                    }
                } else {
#pragma unroll
                    for (int mt = 0; mt < 4; ++mt) {
                        f32x4 av = (mt == 0) ? a0 : (mt == 1) ? a1 : (mt == 2) ? a2 : a3;
#pragma unroll
                        for (int r = 0; r < 4; ++r) {
                            int row = mt * 16 + lg * 4 + r;
                            *(short*)(smem + CV + swz8(lc, row * 2, 128)) = f2bf(av[r] + bias);
                        }
                    }
                }
            }
        }
        __syncthreads();
        const int hb = grp * 64 + lg * 16;
        f32x4 s0 = z, s1 = z, s2 = z, s3 = z;
        {
            bf16x8 qa = *(const bf16x8*)(smem + CQ + swz8(arow, hb, 128));
            bf16x8 k0 = *(const bf16x8*)(smem + CK + swz8(l15, hb, 128));
            bf16x8 k1 = *(const bf16x8*)(smem + CK + swz8(16 + l15, hb, 128));
            bf16x8 k2 = *(const bf16x8*)(smem + CK + swz8(32 + l15, hb, 128));
            bf16x8 k3 = *(const bf16x8*)(smem + CK + swz8(48, hb, 128));
            s0 = MFMA(qa, k0, s0); s1 = MFMA(qa, k1, s1);
            s2 = MFMA(qa, k2, s2); s3 = MFMA(qa, k3, s3);
        }
        const float scale = 0.17677669529663687f;
        float pr[4][4];
#pragma unroll
        for (int rj = 0; rj < 4; ++rj) {
            float v0 = s0[rj] * scale, v1 = s1[rj] * scale;
            float v2 = s2[rj] * scale, v3 = s3[rj] * scale;
            const int c3 = 48 + l15;
            float mx = fmaxf(fmaxf(v0, v1), v2);
            if (c3 < 49) mx = fmaxf(mx, v3);
#pragma unroll
            for (int mm = 1; mm < 16; mm <<= 1) mx = fmaxf(mx, __shfl_xor(mx, mm));
            float e0 = __expf(v0 - mx), e1 = __expf(v1 - mx), e2 = __expf(v2 - mx);
            float e3 = (c3 < 49) ? __expf(v3 - mx) : 0.f;
            float sm = e0 + e1 + e2 + e3;
#pragma unroll
            for (int mm = 1; mm < 16; mm <<= 1) sm += __shfl_xor(sm, mm);
            float inv = 1.f / sm;
            pr[rj][0] = e0 * inv; pr[rj][1] = e1 * inv;
            pr[rj][2] = e2 * inv; pr[rj][3] = e3 * inv;
        }
        __syncthreads();
        char* satt = smem + CQ + grp * 6272;
#pragma unroll
        for (int rj = 0; rj < 4; ++rj) {
            int row = mts * 16 + lg * 4 + rj;
            if (row < 49) {
                *(short*)(satt + swz8(row, l15 * 2, 128)) = f2bf(pr[rj][0]);
                *(short*)(satt + swz8(row, (16 + l15) * 2, 128)) = f2bf(pr[rj][1]);
                *(short*)(satt + swz8(row, (32 + l15) * 2, 128)) = f2bf(pr[rj][2]);
                *(short*)(satt + swz8(row, (48 + l15) * 2, 128)) = f2bf(pr[rj][3]);
            }
        }
        __syncthreads();
        f32x4 o0 = z, o1 = z;
#pragma unroll
        for (int kk = 0; kk < 2; ++kk) {
            const int kb = kk * 64 + lg * 16;
            bf16x8 pa  = *(const bf16x8*)(satt + swz8(arow, kb, 128));
            bf16x8 vb0 = *(const bf16x8*)(smem + CV + swz8(grp * 32 + l15, kb, 128));
            bf16x8 vb1 = *(const bf16x8*)(smem + CV + swz8(grp * 32 + 16 + l15, kb, 128));
            o0 = MFMA(pa, vb0, o0); o1 = MFMA(pa, vb1, o1);
        }
#pragma unroll
        for (int nt = 0; nt < 2; ++nt) {
            f32x4 ov = nt ? o1 : o0;
#pragma unroll
            for (int r = 0; r < 4; ++r) {
                int row = mts * 16 + lg * 4 + r;
                if (row < 49) {
                    int col = hp * 64 + grp * 32 + nt * 16 + l15;
                    *(short*)(smem + OB + swz16(row, col * 2, 512)) = f2bf(ov[r]);
                }
            }
        }
        __syncthreads();
    }

    // ---- out-proj paired (balanced: all waves identical): 4 OB reads / 8 MFMA
    {
        const int j0 = c0, j1 = c0 + 16;
        f32x4 a0 = z, a1 = z, a2 = z, a3 = z;     // ct = 0
        f32x4 c4 = z, c5 = z, c6 = z, c7 = z;     // ct = 1
#pragma unroll
        for (int kk = 0; kk < 8; ++kk) {
            const int cb = kk * 64 + lg * 16;
            bf16x8 f0 = *(const bf16x8*)(smem + OB + swz16(l15, cb, 512));
            bf16x8 f1 = *(const bf16x8*)(smem + OB + swz16(16 + l15, cb, 512));
            bf16x8 f2 = *(const bf16x8*)(smem + OB + swz16(32 + l15, cb, 512));
            bf16x8 f3 = *(const bf16x8*)(smem + OB + swz16(48, cb, 512));
            bf16x8 bw0 = *(const bf16x8*)(WoB + (((size_t)((wv * 2) * 8 + kk) * 64 + lane) << 3));
            bf16x8 bw1 = *(const bf16x8*)(WoB + (((size_t)((wv * 2 + 1) * 8 + kk) * 64 + lane) << 3));
            a0 = MFMA(f0, bw0, a0); a1 = MFMA(f1, bw0, a1);
            a2 = MFMA(f2, bw0, a2); a3 = MFMA(f3, bw0, a3);
            c4 = MFMA(f0, bw1, c4); c5 = MFMA(f1, bw1, c5);
            c6 = MFMA(f2, bw1, c6); c7 = MFMA(f3, bw1, c7);
        }
        const float bias0 = Bo[j0], bias1 = Bo[j1];
#pragma unroll
        for (int mt = 0; mt < 4; ++mt) {
            f32x4 av = (mt == 0) ? a0 : (mt == 1) ? a1 : (mt == 2) ? a2 : a3;
            f32x4 cv = (mt == 0) ? c4 : (mt == 1) ? c5 : (mt == 2) ? c6 : c7;
#pragma unroll
            for (int r = 0; r < 4; ++r) {
                int row = mt * 16 + lg * 4 + r;
                if (row < 49) {
                    short* p0 = (short*)(smem + SW + swz16(row, j0 * 2, 512));
                    *p0 = f2bf(bf2f(*p0) + av[r] + bias0);
                    short* p1 = (short*)(smem + SW + swz16(row, j1 * 2, 512));
                    *p1 = f2bf(bf2f(*p1) + cv[r] + bias1);
                }
            }
        }
    }
    __syncthreads();
    {
        for (int i = tid; i < 49 * 32; i += 512) {
            int row = i >> 5, c8 = (i & 31) * 8;
            bf16x8 v = *(const bf16x8*)(smem + SW + swz16(row, c8 * 2, 512));
            *(bf16x8*)(Rws + ((size_t)bid * 49 + row) * 256 + c8) = v;
        }
    }
}

// ============================================================================
// KB v7 (round-15 exact): 16 waves, chunk=128, swz16 Z/H, H double-buffer,
// XCD swizzle (3136 = 8 * 392). Measured 1176 us.
// ============================================================================
__global__ __launch_bounds__(1024, 1) void mlp_kernel(
    const short* __restrict__ Rws,
    const float* __restrict__ n2w, const float* __restrict__ n2b,
    const short* __restrict__ W1B, const float* __restrict__ B1,
    const short* __restrict__ W2B, const float* __restrict__ B2,
    float* __restrict__ out)
{
    extern __shared__ __align__(16) char smem[];
    constexpr int HB0 = 65536, HB1 = 98304;
    const int tile = (blockIdx.x & 7) * 392 + (blockIdx.x >> 3);
    const int tid = threadIdx.x, wv = tid >> 6, lane = tid & 63;
    const int lg = lane >> 4, l15 = lane & 15;
    const int wm = wv >> 3, wn = wv & 7;
    const int r0 = wm * 64;
    const f32x4 z = {0.f, 0.f, 0.f, 0.f};

#pragma unroll
    for (int it = 0; it < 4; ++it) {
        int e = it * 1024 + tid;
        int row = e >> 5, c8 = (e & 31) * 8;
        bf16x8 v = *(const bf16x8*)(Rws + ((size_t)tile * 128 + row) * 256 + c8);
        *(bf16x8*)(smem + swz16(row, c8 * 2, 512)) = v;
    }
    __syncthreads();
    {
        const int row = tid >> 3, sub = tid & 7;
        bf16x8 vv[4];
        float sum = 0.f, sq = 0.f;
#pragma unroll
        for (int ii = 0; ii < 4; ++ii) {
            vv[ii] = *(const bf16x8*)(smem + swz16(row, (sub * 32 + ii * 8) * 2, 512));
#pragma unroll
            for (int j = 0; j < 8; ++j) { float f = bf2f(vv[ii][j]); sum += f; sq += f * f; }
        }
#pragma unroll
        for (int m = 1; m < 8; m <<= 1) { sum += __shfl_xor(sum, m); sq += __shfl_xor(sq, m); }
        const float mean = sum * (1.f / 256.f);
        const float rstd = rsqrtf(sq * (1.f / 256.f) - mean * mean + 1e-5f);
#pragma unroll
        for (int ii = 0; ii < 4; ++ii) {
            f32x4 w0 = *(const f32x4*)(n2w + sub * 32 + ii * 8);
            f32x4 w1 = *(const f32x4*)(n2w + sub * 32 + ii * 8 + 4);
            f32x4 b0 = *(const f32x4*)(n2b + sub * 32 + ii * 8);
            f32x4 b1 = *(const f32x4*)(n2b + sub * 32 + ii * 8 + 4);
            bf16x8 o;
#pragma unroll
            for (int j = 0; j < 8; ++j) {
                float wj = (j < 4) ? w0[j] : w1[j - 4];
                float bj = (j < 4) ? b0[j] : b1[j - 4];
                o[j] = f2bf((bf2f(vv[ii][j]) - mean) * rstd * wj + bj);
            }
            *(bf16x8*)(smem + swz16(row, (sub * 32 + ii * 8) * 2, 512)) = o;
        }
    }
    __syncthreads();

    f32x4 macc[8];
#pragma unroll
    for (int i = 0; i < 8; ++i) macc[i] = z;

#pragma unroll 1
    for (int c = 0; c < 8; ++c) {
        char* HB = smem + ((c & 1) ? HB1 : HB0);
        f32x4 g1[4];
#pragma unroll
        for (int i = 0; i < 4; ++i) g1[i] = z;
#pragma unroll
        for (int kk = 0; kk < 8; ++kk) {
            const int cb = kk * 64 + lg * 16;
            bf16x8 a0 = *(const bf16x8*)(smem + swz16(r0 + l15,      cb, 512));
            bf16x8 a1 = *(const bf16x8*)(smem + swz16(r0 + 16 + l15, cb, 512));
            bf16x8 a2 = *(const bf16x8*)(smem + swz16(r0 + 32 + l15, cb, 512));
            bf16x8 a3 = *(const bf16x8*)(smem + swz16(r0 + 48 + l15, cb, 512));
            const int t = c * 8 + wn;
            bf16x8 wf = *(const bf16x8*)(W1B + (((size_t)(t * 8 + kk) * 64 + lane) << 3));
            g1[0] = MFMA(a0, wf, g1[0]);
            g1[1] = MFMA(a1, wf, g1[1]);
            g1[2] = MFMA(a2, wf, g1[2]);
            g1[3] = MFMA(a3, wf, g1[3]);
        }
        {
            const int hc = wn * 16 + l15;
            const float bias = B1[c * 128 + hc];
#pragma unroll
            for (int mt = 0; mt < 4; ++mt) {
#pragma unroll
                for (int r = 0; r < 4; ++r) {
                    int row = r0 + mt * 16 + lg * 4 + r;
                    float v = g1[mt][r] + bias;
                    float g = v / (1.f + __expf(-v * (1.595769122f + 0.071354816f * v * v)));
                    *(short*)(HB + swz16(row, hc * 2, 256)) = f2bf(g);
                }
            }
        }
        __syncthreads();
#pragma unroll
        for (int ks = 0; ks < 4; ++ks) {
            const int cb = ks * 64 + lg * 16;
            bf16x8 h0 = *(const bf16x8*)(HB + swz16(r0 + l15,      cb, 256));
            bf16x8 h1 = *(const bf16x8*)(HB + swz16(r0 + 16 + l15, cb, 256));
            bf16x8 h2 = *(const bf16x8*)(HB + swz16(r0 + 32 + l15, cb, 256));
            bf16x8 h3 = *(const bf16x8*)(HB + swz16(r0 + 48 + l15, cb, 256));
#pragma unroll
            for (int ct = 0; ct < 2; ++ct) {
                const int t2 = wn * 2 + ct;
                const int g = c * 4 + ks;
                bf16x8 wf = *(const bf16x8*)(W2B + (((size_t)(t2 * 32 + g) * 64 + lane) << 3));
                macc[ct * 4 + 0] = MFMA(h0, wf, macc[ct * 4 + 0]);
                macc[ct * 4 + 1] = MFMA(h1, wf, macc[ct * 4 + 1]);
                macc[ct * 4 + 2] = MFMA(h2, wf, macc[ct * 4 + 2]);
                macc[ct * 4 + 3] = MFMA(h3, wf, macc[ct * 4 + 3]);
            }
        }
    }
    __syncthreads();
    float* stg = (float*)smem;
#pragma unroll 1
    for (int half = 0; half < 2; ++half) {
        if (wm == half) {
#pragma unroll
            for (int ct = 0; ct < 2; ++ct) {
                const int col = wn * 32 + ct * 16 + l15;
                const float b2v = B2[col];
#pragma unroll
                for (int mt = 0; mt < 4; ++mt) {
#pragma unroll
                    for (int r = 0; r < 4; ++r) {
                        int rl = mt * 16 + lg * 4 + r;
                        size_t t = (size_t)tile * 128 + half * 64 + rl;
                        float rv = bf2f(Rws[t * 256 + col]);
                        stg[rl * 260 + col] = rv + macc[ct * 4 + mt][r] + b2v;
                    }
                }
            }
        }
        __syncthreads();
        for (int i = tid; i < 64 * 256; i += 1024) {
            int cc = i >> 6, rl = i & 63;
            int t = tile * 128 + half * 64 + rl;
            int win = t / 49, l = t - win * 49;
            int b = win >> 10, wh = (win >> 5) & 31, w7 = win & 31;
            out[((size_t)(b * 256 + cc) * 224 + wh * 7 + l / 7) * 224 + w7 * 7 + (l % 7)] =
                stg[rl * 260 + cc];
        }
        __syncthreads();
    }
}

extern "C" void kernel_launch(void* const* d_in, const int* in_sizes, int n_in,
                              void* d_out, int out_size, void* d_ws, size_t ws_size,
                              hipStream_t stream) {
    const float* x   = (const float*)d_in[0];
    const float* n1w = (const float*)d_in[1];
    const float* n1b = (const float*)d_in[2];
    const float* Wq  = (const float*)d_in[3];
    const float* Bq  = (const float*)d_in[4];
    const float* Wo  = (const float*)d_in[5];
    const float* Bo  = (const float*)d_in[6];
    const float* n2w = (const float*)d_in[7];
    const float* n2b = (const float*)d_in[8];
    const float* W1  = (const float*)d_in[9];
    const float* B1  = (const float*)d_in[10];
    const float* W2  = (const float*)d_in[11];
    const float* B2  = (const float*)d_in[12];
    float* out = (float*)d_out;
    (void)in_sizes; (void)n_in; (void)out_size; (void)ws_size;

    short* wsp = (short*)d_ws;
    short* WqF = wsp;                // 196608 shorts (fragment order)
    short* WoF = wsp + 196608;       // 65536
    short* W1F = wsp + 262144;       // 262144
    short* W2F = wsp + 524288;       // 262144  -> weights end at byte 1572864
    short* Rws = wsp + 786432;       // 401408*256 shorts = 205520896 B

    prep_frag<<<96, 256, 0, stream>>>(Wq, WqF, 8, 24576);   // 768x256
    prep_frag<<<32, 256, 0, stream>>>(Wo, WoF, 8, 8192);    // 256x256
    prep_frag<<<128, 256, 0, stream>>>(W1, W1F, 8, 32768);  // 1024x256
    prep_frag<<<128, 256, 0, stream>>>(W2, W2F, 32, 32768); // 256x1024

    swin_attn<<<8192, 512, 76288, stream>>>(x, n1w, n1b, WqF, Bq, WoF, Bo, Rws);
    mlp_kernel<<<3136, 1024, 131072, stream>>>(Rws, n2w, n2b, W1F, B1, W2F, B2, out);
}

// Round 18
// 1957.918 us; speedup vs baseline: 1.1233x; 1.0531x over previous
//
#include <hip/hip_runtime.h>
#include <hip/hip_bf16.h>
#include <math.h>

#define DEVI __device__ __forceinline__
typedef __attribute__((ext_vector_type(8))) short bf16x8;
typedef __attribute__((ext_vector_type(4))) float f32x4;

#define MFMA(a, b, c) __builtin_amdgcn_mfma_f32_16x16x32_bf16((a), (b), (c), 0, 0, 0)

DEVI short f2bf(float f) {
    unsigned u = __builtin_bit_cast(unsigned, f);
    return (short)((u + 0x7FFFu + ((u >> 16) & 1u)) >> 16);
}
DEVI float bf2f(short s) {
    unsigned u = ((unsigned)(unsigned short)s) << 16;
    return __builtin_bit_cast(float, u);
}
// 128B-row tiles: 3-bit row XOR (8 slots)
DEVI int swz8(int row, int cb, int ld) { return row * ld + (cb ^ ((row & 7) << 4)); }
// >=256B-row tiles: 4-bit row XOR (16 slots)
DEVI int swz16(int row, int cb, int ld) { return row * ld + (cb ^ ((row & 15) << 4)); }
DEVI bf16x8 gload_bf8(const float* p) {
    const f32x4* q = (const f32x4*)p;
    f32x4 a = q[0], b = q[1];
    bf16x8 r;
    r[0] = f2bf(a[0]); r[1] = f2bf(a[1]); r[2] = f2bf(a[2]); r[3] = f2bf(a[3]);
    r[4] = f2bf(b[0]); r[5] = f2bf(b[1]); r[6] = f2bf(b[2]); r[7] = f2bf(b[3]);
    return r;
}

// Weight prep: fp32 row-major [rows][Kd] -> bf16 MFMA fragment order.
__global__ void prep_frag(const float* __restrict__ s, short* __restrict__ d,
                          int kd32, int n) {
    int i = blockIdx.x * 256 + threadIdx.x;
    if (i >= n) return;
    int lane = i & 63;
    int gt = i >> 6;
    int g = gt % kd32, tile = gt / kd32;
    int j = tile * 16 + (lane & 15);
    int k0 = g * 32 + (lane >> 4) * 8;
    int Kd = kd32 * 32;
    bf16x8 o = gload_bf8(s + (size_t)j * Kd + k0);
    *(bf16x8*)(d + (size_t)i * 8) = o;
}

// ============================================================================
// KA: round-17 structure (best measured) with softmax 1/sm -> v_rcp_f32
// (saves the precise-division sequence; 2.5e-7 rel err << bf16 rounding).
// ============================================================================
__global__ __launch_bounds__(512, 2) void swin_attn(
    const float* __restrict__ x,
    const float* __restrict__ n1w, const float* __restrict__ n1b,
    const short* __restrict__ WqB, const float* __restrict__ Bq,
    const short* __restrict__ WoB, const float* __restrict__ Bo,
    short* __restrict__ Rws)
{
    extern __shared__ __align__(16) char smem[];
    constexpr int OB = 0, CQ = 25088, CK = 31360, CV = 37632, SW = 50176, ST = 75264;

    // bijective XCD swizzle: 8192 = 8 * 1024
    const int bid = ((blockIdx.x & 7) << 10) + (blockIdx.x >> 3);
    const int b = bid >> 10, wh = (bid >> 5) & 31, w7 = bid & 31;
    const int tid = threadIdx.x, wv = tid >> 6, lane = tid & 63;
    const int lg = lane >> 4, l15 = lane & 15;
    const int c0 = wv * 32 + l15;
    const f32x4 z = {0.f, 0.f, 0.f, 0.f};

    {
        float* sX = (float*)smem;
        const float* xb = x + (size_t)b * (256 * 224 * 224);
        for (int i = tid; i < 256 * 49; i += 512) {
            int c = i / 49, l = i - c * 49;
            int hh = wh * 7 + l / 7, ww = w7 * 7 + (l % 7);
            sX[i] = xb[((size_t)c * 224 + hh) * 224 + ww];
        }
    }
    __syncthreads();
    {
        const int l = tid >> 3, s = tid & 7;
        if (l < 49) {
            const float* sX = (const float*)smem;
            float sum = 0.f, sq = 0.f;
            for (int ii = 0; ii < 32; ++ii) {
                int c = s * 32 + ((ii + tid) & 31);
                float v = sX[c * 49 + l];
                sum += v; sq += v * v;
            }
#pragma unroll
            for (int m = 1; m < 8; m <<= 1) { sum += __shfl_xor(sum, m); sq += __shfl_xor(sq, m); }
            if (s == 0) {
                float mean = sum * (1.f / 256.f);
                ((float*)(smem + ST))[l * 2] = mean;
                ((float*)(smem + ST))[l * 2 + 1] = rsqrtf(sq * (1.f / 256.f) - mean * mean + 1e-5f);
            }
        }
    }
    __syncthreads();
    {
        const float* sX = (const float*)smem;
        const float* st = (const float*)(smem + ST);
        float w0 = n1w[c0], b0 = n1b[c0], w1 = n1w[c0 + 16], b1 = n1b[c0 + 16];
#pragma unroll
        for (int ct = 0; ct < 2; ++ct)
#pragma unroll
        for (int mt = 0; mt < 4; ++mt)
#pragma unroll
        for (int r = 0; r < 4; ++r) {
            int row = mt * 16 + lg * 4 + r, col = c0 + ct * 16;
            if (row < 49) {
                float v = (sX[col * 49 + row] - st[row * 2]) * st[row * 2 + 1] * (ct ? w1 : w0) + (ct ? b1 : b0);
                *(short*)(smem + SW + swz16(row, col * 2, 512)) = f2bf(v);
            }
        }
    }
    __syncthreads();

    const int grp = wv >> 2, mts = wv & 3;
    int arow = mts * 16 + l15; if (arow > 48) arow = 48;
#pragma unroll 1
    for (int hp = 0; hp < 4; ++hp) {
#pragma unroll 1
        for (int sub = 0; sub < 2; ++sub) {
            if (sub == 0 || wv < 4) {
                const int t = sub ? (8 + wv) : wv;
                const int part = t >> 2, tt = t & 3;
                const int lc = tt * 16 + l15;
                const int jw = part * 256 + hp * 64 + lc;
                const int wtile = part * 16 + hp * 4 + tt;
                f32x4 a0 = z, a1 = z, a2 = z, a3 = z;
#pragma unroll
                for (int kk = 0; kk < 8; ++kk) {
                    bf16x8 bw = *(const bf16x8*)(WqB + (((size_t)(wtile * 8 + kk) * 64 + lane) << 3));
                    const int cb = kk * 64 + lg * 16;
                    bf16x8 f0 = *(const bf16x8*)(smem + SW + swz16(l15, cb, 512));
                    bf16x8 f1 = *(const bf16x8*)(smem + SW + swz16(16 + l15, cb, 512));
                    bf16x8 f2 = *(const bf16x8*)(smem + SW + swz16(32 + l15, cb, 512));
                    bf16x8 f3 = *(const bf16x8*)(smem + SW + swz16(48, cb, 512));
                    a0 = MFMA(f0, bw, a0); a1 = MFMA(f1, bw, a1);
                    a2 = MFMA(f2, bw, a2); a3 = MFMA(f3, bw, a3);
                }
                const float bias = Bq[jw];
                if (part < 2) {
                    char* base = smem + (part ? CK : CQ);
#pragma unroll
                    for (int mt = 0; mt < 4; ++mt) {
                        f32x4 av = (mt == 0) ? a0 : (mt == 1) ? a1 : (mt == 2) ? a2 : a3;
#pragma unroll
                        for (int r = 0; r < 4; ++r) {
                            int row = mt * 16 + lg * 4 + r;
                            if (row < 49) *(short*)(base + swz8(row, lc * 2, 128)) = f2bf(av[r] + bias);
                        }
                    }
                } else {
#pragma unroll
                    for (int mt = 0; mt < 4; ++mt) {
                        f32x4 av = (mt == 0) ? a0 : (mt == 1) ? a1 : (mt == 2) ? a2 : a3;
#pragma unroll
                        for (int r = 0; r < 4; ++r) {
                            int row = mt * 16 + lg * 4 + r;
                            *(short*)(smem + CV + swz8(lc, row * 2, 128)) = f2bf(av[r] + bias);
                        }
                    }
                }
            }
        }
        __syncthreads();
        const int hb = grp * 64 + lg * 16;
        f32x4 s0 = z, s1 = z, s2 = z, s3 = z;
        {
            bf16x8 qa = *(const bf16x8*)(smem + CQ + swz8(arow, hb, 128));
            bf16x8 k0 = *(const bf16x8*)(smem + CK + swz8(l15, hb, 128));
            bf16x8 k1 = *(const bf16x8*)(smem + CK + swz8(16 + l15, hb, 128));
            bf16x8 k2 = *(const bf16x8*)(smem + CK + swz8(32 + l15, hb, 128));
            bf16x8 k3 = *(const bf16x8*)(smem + CK + swz8(48, hb, 128));
            s0 = MFMA(qa, k0, s0); s1 = MFMA(qa, k1, s1);
            s2 = MFMA(qa, k2, s2); s3 = MFMA(qa, k3, s3);
        }
        const float scale = 0.17677669529663687f;
        float pr[4][4];
#pragma unroll
        for (int rj = 0; rj < 4; ++rj) {
            float v0 = s0[rj] * scale, v1 = s1[rj] * scale;
            float v2 = s2[rj] * scale, v3 = s3[rj] * scale;
            const int c3 = 48 + l15;
            float mx = fmaxf(fmaxf(v0, v1), v2);
            if (c3 < 49) mx = fmaxf(mx, v3);
#pragma unroll
            for (int mm = 1; mm < 16; mm <<= 1) mx = fmaxf(mx, __shfl_xor(mx, mm));
            float e0 = __expf(v0 - mx), e1 = __expf(v1 - mx), e2 = __expf(v2 - mx);
            float e3 = (c3 < 49) ? __expf(v3 - mx) : 0.f;
            float sm = e0 + e1 + e2 + e3;
#pragma unroll
            for (int mm = 1; mm < 16; mm <<= 1) sm += __shfl_xor(sm, mm);
            float inv = __builtin_amdgcn_rcpf(sm);   // sm >= 1 (max included)
            pr[rj][0] = e0 * inv; pr[rj][1] = e1 * inv;
            pr[rj][2] = e2 * inv; pr[rj][3] = e3 * inv;
        }
        __syncthreads();
        char* satt = smem + CQ + grp * 6272;
#pragma unroll
        for (int rj = 0; rj < 4; ++rj) {
            int row = mts * 16 + lg * 4 + rj;
            if (row < 49) {
                *(short*)(satt + swz8(row, l15 * 2, 128)) = f2bf(pr[rj][0]);
                *(short*)(satt + swz8(row, (16 + l15) * 2, 128)) = f2bf(pr[rj][1]);
                *(short*)(satt + swz8(row, (32 + l15) * 2, 128)) = f2bf(pr[rj][2]);
                *(short*)(satt + swz8(row, (48 + l15) * 2, 128)) = f2bf(pr[rj][3]);
            }
        }
        __syncthreads();
        f32x4 o0 = z, o1 = z;
#pragma unroll
        for (int kk = 0; kk < 2; ++kk) {
            const int kb = kk * 64 + lg * 16;
            bf16x8 pa  = *(const bf16x8*)(satt + swz8(arow, kb, 128));
            bf16x8 vb0 = *(const bf16x8*)(smem + CV + swz8(grp * 32 + l15, kb, 128));
            bf16x8 vb1 = *(const bf16x8*)(smem + CV + swz8(grp * 32 + 16 + l15, kb, 128));
            o0 = MFMA(pa, vb0, o0); o1 = MFMA(pa, vb1, o1);
        }
#pragma unroll
        for (int nt = 0; nt < 2; ++nt) {
            f32x4 ov = nt ? o1 : o0;
#pragma unroll
            for (int r = 0; r < 4; ++r) {
                int row = mts * 16 + lg * 4 + r;
                if (row < 49) {
                    int col = hp * 64 + grp * 32 + nt * 16 + l15;
                    *(short*)(smem + OB + swz16(row, col * 2, 512)) = f2bf(ov[r]);
                }
            }
        }
        __syncthreads();
    }

    // ---- out-proj paired (balanced): 4 OB reads / 8 MFMA per kk ----
    {
        const int j0 = c0, j1 = c0 + 16;
        f32x4 a0 = z, a1 = z, a2 = z, a3 = z;     // ct = 0
        f32x4 c4 = z, c5 = z, c6 = z, c7 = z;     // ct = 1
#pragma unroll
        for (int kk = 0; kk < 8; ++kk) {
            const int cb = kk * 64 + lg * 16;
            bf16x8 f0 = *(const bf16x8*)(smem + OB + swz16(l15, cb, 512));
            bf16x8 f1 = *(const bf16x8*)(smem + OB + swz16(16 + l15, cb, 512));
            bf16x8 f2 = *(const bf16x8*)(smem + OB + swz16(32 + l15, cb, 512));
            bf16x8 f3 = *(const bf16x8*)(smem + OB + swz16(48, cb, 512));
            bf16x8 bw0 = *(const bf16x8*)(WoB + (((size_t)((wv * 2) * 8 + kk) * 64 + lane) << 3));
            bf16x8 bw1 = *(const bf16x8*)(WoB + (((size_t)((wv * 2 + 1) * 8 + kk) * 64 + lane) << 3));
            a0 = MFMA(f0, bw0, a0); a1 = MFMA(f1, bw0, a1);
            a2 = MFMA(f2, bw0, a2); a3 = MFMA(f3, bw0, a3);
            c4 = MFMA(f0, bw1, c4); c5 = MFMA(f1, bw1, c5);
            c6 = MFMA(f2, bw1, c6); c7 = MFMA(f3, bw1, c7);
        }
        const float bias0 = Bo[j0], bias1 = Bo[j1];
#pragma unroll
        for (int mt = 0; mt < 4; ++mt) {
            f32x4 av = (mt == 0) ? a0 : (mt == 1) ? a1 : (mt == 2) ? a2 : a3;
            f32x4 cv = (mt == 0) ? c4 : (mt == 1) ? c5 : (mt == 2) ? c6 : c7;
#pragma unroll
            for (int r = 0; r < 4; ++r) {
                int row = mt * 16 + lg * 4 + r;
                if (row < 49) {
                    short* p0 = (short*)(smem + SW + swz16(row, j0 * 2, 512));
                    *p0 = f2bf(bf2f(*p0) + av[r] + bias0);
                    short* p1 = (short*)(smem + SW + swz16(row, j1 * 2, 512));
                    *p1 = f2bf(bf2f(*p1) + cv[r] + bias1);
                }
            }
        }
    }
    __syncthreads();
    {
        for (int i = tid; i < 49 * 32; i += 512) {
            int row = i >> 5, c8 = (i & 31) * 8;
            bf16x8 v = *(const bf16x8*)(smem + SW + swz16(row, c8 * 2, 512));
            *(bf16x8*)(Rws + ((size_t)bid * 49 + row) * 256 + c8) = v;
        }
    }
}

// ============================================================================
// KB v7 (round-17 exact) + GELU division -> v_rcp_f32 (precise-div sequence
// ~8 VALU ops -> 2; rel err 2.5e-7 << bf16 rounding).
// ============================================================================
__global__ __launch_bounds__(1024, 1) void mlp_kernel(
    const short* __restrict__ Rws,
    const float* __restrict__ n2w, const float* __restrict__ n2b,
    const short* __restrict__ W1B, const float* __restrict__ B1,
    const short* __restrict__ W2B, const float* __restrict__ B2,
    float* __restrict__ out)
{
    extern __shared__ __align__(16) char smem[];
    constexpr int HB0 = 65536, HB1 = 98304;
    const int tile = (blockIdx.x & 7) * 392 + (blockIdx.x >> 3);
    const int tid = threadIdx.x, wv = tid >> 6, lane = tid & 63;
    const int lg = lane >> 4, l15 = lane & 15;
    const int wm = wv >> 3, wn = wv & 7;
    const int r0 = wm * 64;
    const f32x4 z = {0.f, 0.f, 0.f, 0.f};

#pragma unroll
    for (int it = 0; it < 4; ++it) {
        int e = it * 1024 + tid;
        int row = e >> 5, c8 = (e & 31) * 8;
        bf16x8 v = *(const bf16x8*)(Rws + ((size_t)tile * 128 + row) * 256 + c8);
        *(bf16x8*)(smem + swz16(row, c8 * 2, 512)) = v;
    }
    __syncthreads();
    {
        const int row = tid >> 3, sub = tid & 7;
        bf16x8 vv[4];
        float sum = 0.f, sq = 0.f;
#pragma unroll
        for (int ii = 0; ii < 4; ++ii) {
            vv[ii] = *(const bf16x8*)(smem + swz16(row, (sub * 32 + ii * 8) * 2, 512));
#pragma unroll
            for (int j = 0; j < 8; ++j) { float f = bf2f(vv[ii][j]); sum += f; sq += f * f; }
        }
#pragma unroll
        for (int m = 1; m < 8; m <<= 1) { sum += __shfl_xor(sum, m); sq += __shfl_xor(sq, m); }
        const float mean = sum * (1.f / 256.f);
        const float rstd = rsqrtf(sq * (1.f / 256.f) - mean * mean + 1e-5f);
#pragma unroll
        for (int ii = 0; ii < 4; ++ii) {
            f32x4 w0 = *(const f32x4*)(n2w + sub * 32 + ii * 8);
            f32x4 w1 = *(const f32x4*)(n2w + sub * 32 + ii * 8 + 4);
            f32x4 b0 = *(const f32x4*)(n2b + sub * 32 + ii * 8);
            f32x4 b1 = *(const f32x4*)(n2b + sub * 32 + ii * 8 + 4);
            bf16x8 o;
#pragma unroll
            for (int j = 0; j < 8; ++j) {
                float wj = (j < 4) ? w0[j] : w1[j - 4];
                float bj = (j < 4) ? b0[j] : b1[j - 4];
                o[j] = f2bf((bf2f(vv[ii][j]) - mean) * rstd * wj + bj);
            }
            *(bf16x8*)(smem + swz16(row, (sub * 32 + ii * 8) * 2, 512)) = o;
        }
    }
    __syncthreads();

    f32x4 macc[8];
#pragma unroll
    for (int i = 0; i < 8; ++i) macc[i] = z;

#pragma unroll 1
    for (int c = 0; c < 8; ++c) {
        char* HB = smem + ((c & 1) ? HB1 : HB0);
        f32x4 g1[4];
#pragma unroll
        for (int i = 0; i < 4; ++i) g1[i] = z;
#pragma unroll
        for (int kk = 0; kk < 8; ++kk) {
            const int cb = kk * 64 + lg * 16;
            bf16x8 a0 = *(const bf16x8*)(smem + swz16(r0 + l15,      cb, 512));
            bf16x8 a1 = *(const bf16x8*)(smem + swz16(r0 + 16 + l15, cb, 512));
            bf16x8 a2 = *(const bf16x8*)(smem + swz16(r0 + 32 + l15, cb, 512));
            bf16x8 a3 = *(const bf16x8*)(smem + swz16(r0 + 48 + l15, cb, 512));
            const int t = c * 8 + wn;
            bf16x8 wf = *(const bf16x8*)(W1B + (((size_t)(t * 8 + kk) * 64 + lane) << 3));
            g1[0] = MFMA(a0, wf, g1[0]);
            g1[1] = MFMA(a1, wf, g1[1]);
            g1[2] = MFMA(a2, wf, g1[2]);
            g1[3] = MFMA(a3, wf, g1[3]);
        }
        {
            const int hc = wn * 16 + l15;
            const float bias = B1[c * 128 + hc];
#pragma unroll
            for (int mt = 0; mt < 4; ++mt) {
#pragma unroll
                for (int r = 0; r < 4; ++r) {
                    int row = r0 + mt * 16 + lg * 4 + r;
                    float v = g1[mt][r] + bias;
                    float e = __expf(-v * (1.595769122f + 0.071354816f * v * v));
                    float g = v * __builtin_amdgcn_rcpf(1.f + e);
                    *(short*)(HB + swz16(row, hc * 2, 256)) = f2bf(g);
                }
            }
        }
        __syncthreads();
#pragma unroll
        for (int ks = 0; ks < 4; ++ks) {
            const int cb = ks * 64 + lg * 16;
            bf16x8 h0 = *(const bf16x8*)(HB + swz16(r0 + l15,      cb, 256));
            bf16x8 h1 = *(const bf16x8*)(HB + swz16(r0 + 16 + l15, cb, 256));
            bf16x8 h2 = *(const bf16x8*)(HB + swz16(r0 + 32 + l15, cb, 256));
            bf16x8 h3 = *(const bf16x8*)(HB + swz16(r0 + 48 + l15, cb, 256));
#pragma unroll
            for (int ct = 0; ct < 2; ++ct) {
                const int t2 = wn * 2 + ct;
                const int g = c * 4 + ks;
                bf16x8 wf = *(const bf16x8*)(W2B + (((size_t)(t2 * 32 + g) * 64 + lane) << 3));
                macc[ct * 4 + 0] = MFMA(h0, wf, macc[ct * 4 + 0]);
                macc[ct * 4 + 1] = MFMA(h1, wf, macc[ct * 4 + 1]);
                macc[ct * 4 + 2] = MFMA(h2, wf, macc[ct * 4 + 2]);
                macc[ct * 4 + 3] = MFMA(h3, wf, macc[ct * 4 + 3]);
            }
        }
    }
    __syncthreads();
    float* stg = (float*)smem;
#pragma unroll 1
    for (int half = 0; half < 2; ++half) {
        if (wm == half) {
#pragma unroll
            for (int ct = 0; ct < 2; ++ct) {
                const int col = wn * 32 + ct * 16 + l15;
                const float b2v = B2[col];
#pragma unroll
                for (int mt = 0; mt < 4; ++mt) {
#pragma unroll
                    for (int r = 0; r < 4; ++r) {
                        int rl = mt * 16 + lg * 4 + r;
                        size_t t = (size_t)tile * 128 + half * 64 + rl;
                        float rv = bf2f(Rws[t * 256 + col]);
                        stg[rl * 260 + col] = rv + macc[ct * 4 + mt][r] + b2v;
                    }
                }
            }
        }
        __syncthreads();
        for (int i = tid; i < 64 * 256; i += 1024) {
            int cc = i >> 6, rl = i & 63;
            int t = tile * 128 + half * 64 + rl;
            int win = t / 49, l = t - win * 49;
            int b = win >> 10, wh = (win >> 5) & 31, w7 = win & 31;
            out[((size_t)(b * 256 + cc) * 224 + wh * 7 + l / 7) * 224 + w7 * 7 + (l % 7)] =
                stg[rl * 260 + cc];
        }
        __syncthreads();
    }
}

extern "C" void kernel_launch(void* const* d_in, const int* in_sizes, int n_in,
                              void* d_out, int out_size, void* d_ws, size_t ws_size,
                              hipStream_t stream) {
    const float* x   = (const float*)d_in[0];
    const float* n1w = (const float*)d_in[1];
    const float* n1b = (const float*)d_in[2];
    const float* Wq  = (const float*)d_in[3];
    const float* Bq  = (const float*)d_in[4];
    const float* Wo  = (const float*)d_in[5];
    const float* Bo  = (const float*)d_in[6];
    const float* n2w = (const float*)d_in[7];
    const float* n2b = (const float*)d_in[8];
    const float* W1  = (const float*)d_in[9];
    const float* B1  = (const float*)d_in[10];
    const float* W2  = (const float*)d_in[11];
    const float* B2  = (const float*)d_in[12];
    float* out = (float*)d_out;
    (void)in_sizes; (void)n_in; (void)out_size; (void)ws_size;

    short* wsp = (short*)d_ws;
    short* WqF = wsp;                // 196608 shorts (fragment order)
    short* WoF = wsp + 196608;       // 65536
    short* W1F = wsp + 262144;       // 262144
    short* W2F = wsp + 524288;       // 262144  -> weights end at byte 1572864
    short* Rws = wsp + 786432;       // 401408*256 shorts = 205520896 B

    prep_frag<<<96, 256, 0, stream>>>(Wq, WqF, 8, 24576);   // 768x256
    prep_frag<<<32, 256, 0, stream>>>(Wo, WoF, 8, 8192);    // 256x256
    prep_frag<<<128, 256, 0, stream>>>(W1, W1F, 8, 32768);  // 1024x256
    prep_frag<<<128, 256, 0, stream>>>(W2, W2F, 32, 32768); // 256x1024

    swin_attn<<<8192, 512, 76288, stream>>>(x, n1w, n1b, WqF, Bq, WoF, Bo, Rws);
    mlp_kernel<<<3136, 1024, 131072, stream>>>(Rws, n2w, n2b, W1F, B1, W2F, B2, out);
}